// Round 5
// baseline (275.986 us; speedup 1.0000x reference)
//
#include <hip/hip_runtime.h>
#include <hip/hip_bf16.h>
#include <math.h>

#define NPTS   16384
#define NCH    8
#define HID    256
#define MT     64    // rows per block
#define LSTR   264   // LDS activation row stride (256 + 8 pad) in bf16 elems
#define MAXTB  2048  // table slots: slot s -> chart s&7, tile s>>3 (XCD swizzle)

typedef short bf16x8 __attribute__((ext_vector_type(8)));
typedef float f32x4  __attribute__((ext_vector_type(4)));

__device__ __forceinline__ float bf2f(unsigned short u){
  union { unsigned int i; float f; } v; v.i = ((unsigned int)u) << 16; return v.f;
}
__device__ __forceinline__ unsigned short f2bf(float f){
  union { float f; unsigned int i; } v; v.f = f;
  unsigned int x = v.i;
  return (unsigned short)((x + 0x7fffu + ((x >> 16) & 1u)) >> 16); // RNE
}

// ---- fused prologue: weight transpose (776 blocks) + bucketing (1 block) --
// blocks 0..767:  Wth[c][l][n][k] = bf16(Wh[c][l][k][n])   (48 mats x 16 tiles)
// blocks 768..775: Wt0[c][n][k]   = bf16(W0[c][k][n]), k padded 29->32
// block 776:      hist + prefix + table + scatter (ballot-based)

__global__ __launch_bounds__(256) void prep_tr_k(
    const float* __restrict__ Wh, const float* __restrict__ W0,
    const int* __restrict__ midx,
    unsigned short* __restrict__ Wth, unsigned short* __restrict__ Wt0,
    int* __restrict__ counts, int* __restrict__ base,
    int* __restrict__ table, int* __restrict__ bucket){
  int bid = blockIdx.x;
  int tid = threadIdx.x;
  if (bid < 768){
    __shared__ __align__(16) float tile[64][68];
    int mat = bid >> 4;
    int t4  = bid & 15;
    int kr  = (t4 >> 2) << 6;
    int nc  = (t4 & 3) << 6;
    const float* src = Wh + (size_t)mat * 65536;
    unsigned short* dst = Wth + (size_t)mat * 65536;
    int r  = tid >> 2;
    int cs = (tid & 3) << 4;
    const float* sp = &src[(kr + r) * 256 + nc + cs];
    *(float4*)&tile[r][cs]      = *(const float4*)&sp[0];
    *(float4*)&tile[r][cs + 4]  = *(const float4*)&sp[4];
    *(float4*)&tile[r][cs + 8]  = *(const float4*)&sp[8];
    *(float4*)&tile[r][cs + 12] = *(const float4*)&sp[12];
    __syncthreads();
    int n  = tid >> 2;
    int ks = (tid & 3) << 4;
    __align__(16) unsigned short tmp[16];
    #pragma unroll
    for (int j = 0; j < 16; j++) tmp[j] = f2bf(tile[ks + j][n]);
    *(uint4*)&dst[(nc + n) * 256 + kr + ks]     = *(const uint4*)&tmp[0];
    *(uint4*)&dst[(nc + n) * 256 + kr + ks + 8] = *(const uint4*)&tmp[8];
  } else if (bid < 776){
    int c = bid - 768;
    for (int j = 0; j < 32; j++){
      int i = j * 256 + tid;          // 8192 elems: n = i>>5, k = i&31
      int k = i & 31, n = i >> 5;
      unsigned short v = 0;
      if (k < 29) v = f2bf(W0[(c * 29 + k) * 256 + n]);
      Wt0[c * 8192 + i] = v;
    }
  } else {
    __shared__ int h[NCH], bs[NCH], cur[NCH], tn[NCH];
    int lane = tid & 63;
    if (tid < NCH){ h[tid] = 0; cur[tid] = 0; }
    __syncthreads();
    // ballot histogram
    for (int i = tid; i < NPTS; i += 256){
      int c = midx[i];
      #pragma unroll
      for (int cc = 0; cc < NCH; cc++){
        unsigned long long mask = __ballot(c == cc);
        if (mask && lane == (__ffsll((long long)mask) - 1))
          atomicAdd(&h[cc], __popcll(mask));
      }
    }
    __syncthreads();
    if (tid == 0){
      int off = 0;
      for (int c = 0; c < NCH; c++){
        bs[c] = off; off += h[c];
        tn[c] = (h[c] + MT - 1) / MT;
      }
    }
    __syncthreads();
    if (tid < NCH){ counts[tid] = h[tid]; base[tid] = bs[tid]; }
    // table: slot s -> chart s&7, tile s>>3  (XCD swizzle: chart == s % 8)
    for (int t = tid; t < MAXTB; t += 256){
      int c = t & 7, tt = t >> 3;
      table[2*t]   = (tt < tn[c]) ? c : -1;
      table[2*t+1] = tt;
    }
    // ballot scatter (order within chart irrelevant)
    for (int i = tid; i < NPTS; i += 256){
      int c = midx[i];
      #pragma unroll
      for (int cc = 0; cc < NCH; cc++){
        unsigned long long mask = __ballot(c == cc);
        if (!mask) continue;
        int leader = __ffsll((long long)mask) - 1;
        int wbase = 0;
        if (lane == leader) wbase = atomicAdd(&cur[cc], __popcll(mask));
        wbase = __shfl(wbase, leader);
        if (c == cc){
          int off = __popcll(mask & ((1ull << lane) - 1));
          bucket[bs[cc] + wbase + off] = i;
        }
      }
    }
  }
}

// ---- main fused MLP kernel (64-row tiles, deep B-prefetch) ----------------

__global__ __launch_bounds__(256, 2) void mlp_k(
    const float* __restrict__ x,
    const float* __restrict__ proc,
    const float* __restrict__ b0,
    const float* __restrict__ bh,
    const float* __restrict__ Wl,
    const float* __restrict__ bl,
    const unsigned short* __restrict__ Wt0,
    const unsigned short* __restrict__ Wth,
    const int* __restrict__ counts,
    const int* __restrict__ base,
    const int* __restrict__ table,
    const int* __restrict__ bucket,
    float* __restrict__ out)
{
  __shared__ __align__(16) unsigned short hA[MT * LSTR];
  __shared__ __align__(16) unsigned short hB[MT * LSTR];
  __shared__ int ridx[MT];

  int chart = table[blockIdx.x * 2];
  if (chart < 0) return;
  int tile = table[blockIdx.x * 2 + 1];
  int cbase = base[chart];
  int cnt = counts[chart] - tile * MT;
  if (cnt > MT) cnt = MT;

  int tid  = threadIdx.x;
  int lane = tid & 63;
  int wv   = tid >> 6;
  int l15  = lane & 15;
  int quad = lane >> 4;

  // Phase A: gather + positional encoding into hA[row][0..31]
  if (tid < MT){
    int row = tid;
    int g = (row < cnt) ? bucket[cbase + tile * MT + row] : -1;
    ridx[row] = g;
    unsigned short* rowp = &hA[row * LSTR];
    if (g >= 0){
      float xv0 = x[g*3+0], xv1 = x[g*3+1], xv2 = x[g*3+2];
      rowp[0] = f2bf(xv0); rowp[1] = f2bf(xv1); rowp[2] = f2bf(xv2);
      #pragma unroll
      for (int d = 1; d <= 4; d++){
        float s = (float)(1 << d) * 3.14159265358979323846f;
        int o = 3 + (d - 1) * 6;
        rowp[o+0] = f2bf(sinf(s*xv0)); rowp[o+1] = f2bf(sinf(s*xv1)); rowp[o+2] = f2bf(sinf(s*xv2));
        rowp[o+3] = f2bf(cosf(s*xv0)); rowp[o+4] = f2bf(cosf(s*xv1)); rowp[o+5] = f2bf(cosf(s*xv2));
      }
      rowp[27] = f2bf(proc[0]); rowp[28] = f2bf(proc[1]);
      rowp[29] = 0; rowp[30] = 0; rowp[31] = 0;
    } else {
      #pragma unroll
      for (int k = 0; k < 32; k++) rowp[k] = 0;
    }
  }
  __syncthreads();

  int nb = wv * 64;   // this wave's output-column base
  f32x4 acc[4][4];

  // Layer 0: (64x32) @ (32x256), single K-step
  {
    const unsigned short* W0p = Wt0 + chart * 8192;
    bf16x8 a[4], b[4];
    #pragma unroll
    for (int nt = 0; nt < 4; nt++)
      b[nt] = *(const bf16x8*)&W0p[(nb + nt * 16 + l15) * 32 + quad * 8];
    #pragma unroll
    for (int mt = 0; mt < 4; mt++)
      a[mt] = *(const bf16x8*)&hA[(mt * 16 + l15) * LSTR + quad * 8];
    #pragma unroll
    for (int mt = 0; mt < 4; mt++)
      #pragma unroll
      for (int nt = 0; nt < 4; nt++){
        f32x4 z = {0.f, 0.f, 0.f, 0.f};
        acc[mt][nt] = __builtin_amdgcn_mfma_f32_16x16x32_bf16(a[mt], b[nt], z, 0, 0, 0);
      }
    const float* b0c = b0 + chart * 256;
    #pragma unroll
    for (int nt = 0; nt < 4; nt++){
      int col = nb + nt * 16 + l15;
      float bias = b0c[col];
      #pragma unroll
      for (int mt = 0; mt < 4; mt++)
        #pragma unroll
        for (int r = 0; r < 4; r++){
          float v = acc[mt][nt][r] + bias;
          v = v > 0.f ? v : 0.f;
          hB[(mt * 16 + quad * 4 + r) * LSTR + col] = f2bf(v);
        }
    }
  }
  __syncthreads();

  // 6 hidden layers: (64x256) @ (256x256) with 4-deep B prefetch
  unsigned short* hin  = hB;
  unsigned short* hout = hA;
  for (int l = 0; l < 6; l++){
    const unsigned short* wl = Wth + ((size_t)(chart * 6 + l) << 16)
                             + (size_t)(nb + l15) * 256 + quad * 8;
    const float* bp = bh + (chart * 6 + l) * 256;
    #pragma unroll
    for (int mt = 0; mt < 4; mt++)
      #pragma unroll
      for (int nt = 0; nt < 4; nt++)
        acc[mt][nt] = (f32x4){0.f, 0.f, 0.f, 0.f};

    bf16x8 bb[8][4];
    #pragma unroll
    for (int p = 0; p < 4; p++)
      #pragma unroll
      for (int nt = 0; nt < 4; nt++)
        bb[p][nt] = *(const bf16x8*)&wl[nt * 4096 + p * 32];

    #pragma unroll
    for (int kk = 0; kk < 8; kk++){
      if (kk + 4 < 8){
        #pragma unroll
        for (int nt = 0; nt < 4; nt++)
          bb[kk+4][nt] = *(const bf16x8*)&wl[nt * 4096 + (kk+4) * 32];
      }
      bf16x8 a[4];
      #pragma unroll
      for (int mt = 0; mt < 4; mt++)
        a[mt] = *(const bf16x8*)&hin[(mt * 16 + l15) * LSTR + kk * 32 + quad * 8];
      #pragma unroll
      for (int nt = 0; nt < 4; nt++)
        #pragma unroll
        for (int mt = 0; mt < 4; mt++)
          acc[mt][nt] = __builtin_amdgcn_mfma_f32_16x16x32_bf16(a[mt], bb[kk][nt], acc[mt][nt], 0, 0, 0);
    }

    #pragma unroll
    for (int nt = 0; nt < 4; nt++){
      int col = nb + nt * 16 + l15;
      float bias = bp[col];
      #pragma unroll
      for (int mt = 0; mt < 4; mt++)
        #pragma unroll
        for (int r = 0; r < 4; r++){
          float v = acc[mt][nt][r] + bias;
          v = v > 0.f ? v : 0.f;
          hout[(mt * 16 + quad * 4 + r) * LSTR + col] = f2bf(v);
        }
    }
    __syncthreads();
    unsigned short* t = hin; hin = hout; hout = t;
  }

  // Final layer: (64x256) @ (256x2) + sigmoid, scatter to out (fp32)
  {
    int m = tid >> 2;          // 0..63 rows
    int p = tid & 3;           // 4 threads/row, 64 k each
    const unsigned short* hrow = hin + m * LSTR + p * 64;
    const float* Wlp = Wl + chart * 512 + p * 128;
    float s0 = 0.f, s1 = 0.f;
    #pragma unroll 8
    for (int k = 0; k < 64; k += 2){
      float4 w4 = *(const float4*)&Wlp[k * 2];
      unsigned int h2 = *(const unsigned int*)&hrow[k];
      float hv0 = bf2f((unsigned short)(h2 & 0xffff));
      float hv1 = bf2f((unsigned short)(h2 >> 16));
      s0 += hv0 * w4.x + hv1 * w4.z;
      s1 += hv0 * w4.y + hv1 * w4.w;
    }
    s0 += __shfl_xor(s0, 1); s0 += __shfl_xor(s0, 2);
    s1 += __shfl_xor(s1, 1); s1 += __shfl_xor(s1, 2);
    if (p == 0){
      int g = ridx[m];
      if (g >= 0){
        float o0 = 1.f / (1.f + __expf(-(s0 + bl[chart*2+0])));
        float o1 = 1.f / (1.f + __expf(-(s1 + bl[chart*2+1])));
        *(float2*)&out[(size_t)g * 2] = make_float2(o0, o1);
      }
    }
  }
}

// ---- launch ---------------------------------------------------------------

extern "C" void kernel_launch(void* const* d_in, const int* in_sizes, int n_in,
                              void* d_out, int out_size, void* d_ws, size_t ws_size,
                              hipStream_t stream){
  const float* x    = (const float*)d_in[0];
  const float* proc = (const float*)d_in[1];
  const float* W0   = (const float*)d_in[2];
  const float* b0   = (const float*)d_in[3];
  const float* Wh   = (const float*)d_in[4];
  const float* bh   = (const float*)d_in[5];
  const float* Wl   = (const float*)d_in[6];
  const float* bl   = (const float*)d_in[7];
  const int* midx = (const int*)d_in[8];
  float* out = (float*)d_out;

  char* ws = (char*)d_ws;
  int* counts  = (int*)ws;                    // 8 ints
  int* base    = counts + 8;                  // 8 ints
  int* table   = counts + 16;                 // MAXTB*2 ints
  int* bucket  = table + 2 * MAXTB;           // NPTS ints
  size_t off = (((size_t)(16 + 2 * MAXTB + NPTS)) * 4 + 15) & ~(size_t)15;
  unsigned short* Wt0 = (unsigned short*)(ws + off);          // 8*256*32 bf16
  unsigned short* Wth = Wt0 + NCH * 8192;                     // 8*6*256*256 bf16

  hipLaunchKernelGGL(prep_tr_k, dim3(777),   dim3(256), 0, stream,
                     Wh, W0, midx, Wth, Wt0, counts, base, table, bucket);
  hipLaunchKernelGGL(mlp_k,     dim3(MAXTB), dim3(256), 0, stream,
                     x, proc, b0, bh, Wl, bl, Wt0, Wth, counts, base, table, bucket, out);
}

// Round 6
// 254.891 us; speedup vs baseline: 1.0828x; 1.0828x over previous
//
#include <hip/hip_runtime.h>
#include <hip/hip_bf16.h>
#include <math.h>

#define NPTS   16384
#define NCH    8
#define MT     64    // rows per block
#define LSTR   272   // LDS activation row stride (ushorts); 272*2/4 % 32 = 8 -> 4-way worst
#define MAXTB  2048  // table slots: slot s -> chart s&7, tile s>>3

typedef short bf16x8 __attribute__((ext_vector_type(8)));
typedef float f32x4  __attribute__((ext_vector_type(4)));

__device__ __forceinline__ float bf2f(unsigned short u){
  union { unsigned int i; float f; } v; v.i = ((unsigned int)u) << 16; return v.f;
}
__device__ __forceinline__ unsigned short f2bf(float f){
  union { float f; unsigned int i; } v; v.f = f;
  unsigned int x = v.i;
  return (unsigned short)((x + 0x7fffu + ((x >> 16) & 1u)) >> 16); // RNE
}

__device__ __forceinline__ void dma16(const void* g, void* l){
  __builtin_amdgcn_global_load_lds(
      (const __attribute__((address_space(1))) unsigned int*)g,
      (__attribute__((address_space(3))) unsigned int*)l, 16, 0, 0);
}

// ---- K1: weight transpose (776 blocks) + parallel histogram (64 blocks) ---

__global__ __launch_bounds__(256) void prep1_k(
    const float* __restrict__ Wh, const float* __restrict__ W0,
    const int* __restrict__ midx,
    unsigned short* __restrict__ Wth, unsigned short* __restrict__ Wt0,
    int* __restrict__ counts){
  int bid = blockIdx.x, tid = threadIdx.x;
  if (bid < 768){
    __shared__ __align__(16) float tile[64][68];
    int mat = bid >> 4;
    int t4  = bid & 15;
    int kr  = (t4 >> 2) << 6;
    int nc  = (t4 & 3) << 6;
    const float* src = Wh + (size_t)mat * 65536;
    unsigned short* dst = Wth + (size_t)mat * 65536;
    int r  = tid >> 2;
    int cs = (tid & 3) << 4;
    const float* sp = &src[(kr + r) * 256 + nc + cs];
    *(float4*)&tile[r][cs]      = *(const float4*)&sp[0];
    *(float4*)&tile[r][cs + 4]  = *(const float4*)&sp[4];
    *(float4*)&tile[r][cs + 8]  = *(const float4*)&sp[8];
    *(float4*)&tile[r][cs + 12] = *(const float4*)&sp[12];
    __syncthreads();
    int n  = tid >> 2;
    int ks = (tid & 3) << 4;
    __align__(16) unsigned short tmp[16];
    #pragma unroll
    for (int j = 0; j < 16; j++) tmp[j] = f2bf(tile[ks + j][n]);
    *(uint4*)&dst[(nc + n) * 256 + kr + ks]     = *(const uint4*)&tmp[0];
    *(uint4*)&dst[(nc + n) * 256 + kr + ks + 8] = *(const uint4*)&tmp[8];
  } else if (bid < 776){
    int c = bid - 768;
    for (int j = 0; j < 32; j++){
      int i = j * 256 + tid;
      int k = i & 31, n = i >> 5;
      unsigned short v = 0;
      if (k < 29) v = f2bf(W0[(c * 29 + k) * 256 + n]);
      Wt0[c * 8192 + i] = v;
    }
  } else {
    int i = (bid - 776) * 256 + tid;
    int c = midx[i];
    int lane = tid & 63;
    #pragma unroll
    for (int cc = 0; cc < NCH; cc++){
      unsigned long long m = __ballot(c == cc);
      if (m && lane == (int)(__ffsll((long long)m) - 1))
        atomicAdd(&counts[cc], __popcll(m));
    }
  }
}

// ---- K2: scatter (64 blocks) + table/base build (1 block) -----------------

__global__ __launch_bounds__(256) void prep2_k(
    const int* __restrict__ midx, const int* __restrict__ counts,
    int* __restrict__ cursors, int* __restrict__ base,
    int* __restrict__ table, int* __restrict__ bucket){
  int bid = blockIdx.x, tid = threadIdx.x;
  int cnt[NCH], bs[NCH];
  int off = 0;
  #pragma unroll
  for (int c = 0; c < NCH; c++){ cnt[c] = counts[c]; bs[c] = off; off += cnt[c]; }
  if (bid < 64){
    int i = bid * 256 + tid;
    int c = midx[i];
    int lane = tid & 63;
    #pragma unroll
    for (int cc = 0; cc < NCH; cc++){
      unsigned long long m = __ballot(c == cc);
      if (!m) continue;
      int leader = (int)(__ffsll((long long)m) - 1);
      int wb = 0;
      if (lane == leader) wb = atomicAdd(&cursors[cc], __popcll(m));
      wb = __shfl(wb, leader);
      if (c == cc){
        int rk = __popcll(m & ((1ull << lane) - 1));
        bucket[bs[cc] + wb + rk] = i;
      }
    }
  } else {
    if (tid < NCH) base[tid] = bs[tid];
    for (int t = tid; t < MAXTB; t += 256){
      int c = t & 7, tt = t >> 3;
      int tiles = (cnt[c] + MT - 1) / MT;
      table[2*t]   = (tt < tiles) ? c : -1;
      table[2*t+1] = tt;
    }
  }
}

// ---- main fused MLP: LDS-staged weights via async DMA, fine-grained vmcnt --

__global__ __launch_bounds__(256) void mlp_k(
    const float* __restrict__ x,
    const float* __restrict__ proc,
    const float* __restrict__ b0,
    const float* __restrict__ bh,
    const float* __restrict__ Wl,
    const float* __restrict__ bl,
    const unsigned short* __restrict__ Wt0,
    const unsigned short* __restrict__ Wth,
    const int* __restrict__ counts,
    const int* __restrict__ base,
    const int* __restrict__ table,
    const int* __restrict__ bucket,
    float* __restrict__ out)
{
  __shared__ __align__(16) unsigned short act0[MT * LSTR];
  __shared__ __align__(16) unsigned short act1[MT * LSTR];
  __shared__ __align__(16) unsigned short wbuf[2][16384]; // 2 x 32 KB (2048 slots of 16B)
  __shared__ float biasb[7 * 256];
  __shared__ float wlb[512];
  __shared__ int ridx[MT];

  int chart = table[blockIdx.x * 2];
  if (chart < 0) return;
  int tile = table[blockIdx.x * 2 + 1];
  int cbase = base[chart];
  int cnt = counts[chart] - tile * MT;
  if (cnt > MT) cnt = MT;

  int tid  = threadIdx.x;
  int lane = tid & 63;
  int wv   = tid >> 6;
  int l15  = lane & 15;
  int quad = lane >> 4;

  const unsigned short* Wc = Wth + ((size_t)(chart * 6) << 16);

  // --- async DMA issue: one 32KB chunk = cols [c*64, c*64+64) x k[0,256) of layer l (1..6)
  // LDS slot s holds global (n_local = s>>5, kc = (s&31) ^ (s>>5 & 31)); XOR-swizzle
  // makes B-fragment ds_reads conflict-free. Wave w stages slots [w*512, w*512+512).
  #define ISSUE_CHUNK(l, c, buf) do {                                          \
    const unsigned short* Wl_ = Wc + (((size_t)((l) - 1)) << 16);              \
    _Pragma("unroll")                                                          \
    for (int it = 0; it < 8; it++){                                            \
      int s  = (wv * 8 + it) * 64 + lane;                                      \
      int nl = s >> 5;                                                         \
      int kc = (s & 31) ^ (nl & 31);                                           \
      const unsigned short* g = Wl_ + (size_t)(((c) * 64 + nl) * 32 + kc) * 8; \
      dma16(g, &wbuf[buf][(size_t)(wv * 8 + it) * 512]);                       \
    }                                                                          \
  } while (0)

  // kick off layer-1 chunks 0,1 immediately (weights independent of activations)
  ISSUE_CHUNK(1, 0, 0);
  ISSUE_CHUNK(1, 1, 1);

  // stage biases + Wl into LDS (keeps steady-loop vmcnt stream pure)
  biasb[tid] = b0[chart * 256 + tid];
  #pragma unroll
  for (int j = 0; j < 6; j++)
    biasb[(j + 1) * 256 + tid] = bh[(chart * 6 + j) * 256 + tid];
  wlb[tid]       = Wl[chart * 512 + tid];
  wlb[256 + tid] = Wl[chart * 512 + 256 + tid];

  // positional encoding -> act0 rows
  if (tid < MT){
    int row = tid;
    int g = (row < cnt) ? bucket[cbase + tile * MT + row] : -1;
    ridx[row] = g;
    unsigned short* rowp = &act0[row * LSTR];
    if (g >= 0){
      float xv0 = x[g*3+0], xv1 = x[g*3+1], xv2 = x[g*3+2];
      rowp[0] = f2bf(xv0); rowp[1] = f2bf(xv1); rowp[2] = f2bf(xv2);
      #pragma unroll
      for (int d = 1; d <= 4; d++){
        float s = (float)(1 << d) * 3.14159265358979323846f;
        int o = 3 + (d - 1) * 6;
        rowp[o+0] = f2bf(sinf(s*xv0)); rowp[o+1] = f2bf(sinf(s*xv1)); rowp[o+2] = f2bf(sinf(s*xv2));
        rowp[o+3] = f2bf(cosf(s*xv0)); rowp[o+4] = f2bf(cosf(s*xv1)); rowp[o+5] = f2bf(cosf(s*xv2));
      }
      rowp[27] = f2bf(proc[0]); rowp[28] = f2bf(proc[1]);
      rowp[29] = 0; rowp[30] = 0; rowp[31] = 0;
    } else {
      #pragma unroll
      for (int k = 0; k < 32; k++) rowp[k] = 0;
    }
  }
  __syncthreads();   // full drain once: PE + bias staging + c0/c1 DMA complete

  f32x4 acc[16];
  const f32x4 zz = {0.f, 0.f, 0.f, 0.f};

  // Layer 0: (64x32)@(32x256); wave w owns rows 16w..16w+15, all 256 cols
  {
    const unsigned short* W0p = Wt0 + chart * 8192;
    bf16x8 a0 = *(const bf16x8*)&act0[(wv * 16 + l15) * LSTR + quad * 8];
    #pragma unroll
    for (int nt = 0; nt < 16; nt++){
      bf16x8 b = *(const bf16x8*)&W0p[(nt * 16 + l15) * 32 + quad * 8];
      acc[nt] = __builtin_amdgcn_mfma_f32_16x16x32_bf16(a0, b, zz, 0, 0, 0);
    }
    #pragma unroll
    for (int nt = 0; nt < 16; nt++){
      int col = nt * 16 + l15;
      float bias = biasb[col];
      #pragma unroll
      for (int r = 0; r < 4; r++){
        float v = acc[nt][r] + bias;
        v = v > 0.f ? v : 0.f;
        act1[(wv * 16 + quad * 4 + r) * LSTR + col] = f2bf(v);
      }
    }
  }
  __syncthreads();   // drain (no DMA outstanding here)

  // 6 hidden layers x 4 chunks; double-buffered DMA, vmcnt(8) pipeline
  bf16x8 areg[8];
  for (int lc = 0; lc < 24; lc++){
    int l = 1 + (lc >> 2), c = lc & 3, buf = lc & 1;

    // barrier1: my chunk's DMA done (8 newer may remain in flight)
    if (lc + 1 < 24) asm volatile("s_waitcnt vmcnt(8) lgkmcnt(0)\n\ts_barrier" ::: "memory");
    else             asm volatile("s_waitcnt vmcnt(0) lgkmcnt(0)\n\ts_barrier" ::: "memory");

    const unsigned short* ain = (l & 1) ? act1 : act0;
    if (c == 0){
      #pragma unroll
      for (int kk = 0; kk < 8; kk++)
        areg[kk] = *(const bf16x8*)&ain[(wv * 16 + l15) * LSTR + kk * 32 + quad * 8];
    }
    #pragma unroll
    for (int kk = 0; kk < 8; kk++){
      int kc = kk * 4 + quad;
      #pragma unroll
      for (int nt = 0; nt < 4; nt++){
        int nl = nt * 16 + l15;
        int slot = nl * 32 + (kc ^ (nl & 31));
        bf16x8 b = *(const bf16x8*)&wbuf[buf][slot * 8];
        f32x4 cin = (kk == 0) ? zz : acc[c * 4 + nt];
        acc[c * 4 + nt] = __builtin_amdgcn_mfma_f32_16x16x32_bf16(areg[kk], b, cin, 0, 0, 0);
      }
    }
    if (c == 3){
      unsigned short* aout = (l & 1) ? act0 : act1;
      #pragma unroll
      for (int nt = 0; nt < 16; nt++){
        int col = nt * 16 + l15;
        float bias = biasb[l * 256 + col];
        #pragma unroll
        for (int r = 0; r < 4; r++){
          float v = acc[nt][r] + bias;
          v = v > 0.f ? v : 0.f;
          aout[(wv * 16 + quad * 4 + r) * LSTR + col] = f2bf(v);
        }
      }
    }
    // barrier2: all waves done reading wbuf[buf] (+ epilogue LDS writes visible)
    asm volatile("s_waitcnt lgkmcnt(0)\n\ts_barrier" ::: "memory");
    if (lc + 2 < 24){
      int lc2 = lc + 2;
      ISSUE_CHUNK(1 + (lc2 >> 2), lc2 & 3, lc2 & 1);
    }
  }

  // Final layer: (64x256)@(256x2) + sigmoid; final acts in act1 (layer 6 out)
  {
    int m = tid >> 2;
    int p = tid & 3;
    const unsigned short* hrow = act1 + m * LSTR + p * 64;
    const float* wlp = wlb + p * 128;
    float s0 = 0.f, s1 = 0.f;
    #pragma unroll 8
    for (int k = 0; k < 64; k += 2){
      float4 w4 = *(const float4*)&wlp[k * 2];
      unsigned int h2 = *(const unsigned int*)&hrow[k];
      float hv0 = bf2f((unsigned short)(h2 & 0xffff));
      float hv1 = bf2f((unsigned short)(h2 >> 16));
      s0 += hv0 * w4.x + hv1 * w4.z;
      s1 += hv0 * w4.y + hv1 * w4.w;
    }
    s0 += __shfl_xor(s0, 1); s0 += __shfl_xor(s0, 2);
    s1 += __shfl_xor(s1, 1); s1 += __shfl_xor(s1, 2);
    if (p == 0){
      int g = ridx[m];
      if (g >= 0){
        float o0 = 1.f / (1.f + __expf(-(s0 + bl[chart*2+0])));
        float o1 = 1.f / (1.f + __expf(-(s1 + bl[chart*2+1])));
        *(float2*)&out[(size_t)g * 2] = make_float2(o0, o1);
      }
    }
  }
}

// ---- launch ---------------------------------------------------------------

extern "C" void kernel_launch(void* const* d_in, const int* in_sizes, int n_in,
                              void* d_out, int out_size, void* d_ws, size_t ws_size,
                              hipStream_t stream){
  const float* x    = (const float*)d_in[0];
  const float* proc = (const float*)d_in[1];
  const float* W0   = (const float*)d_in[2];
  const float* b0   = (const float*)d_in[3];
  const float* Wh   = (const float*)d_in[4];
  const float* bh   = (const float*)d_in[5];
  const float* Wl   = (const float*)d_in[6];
  const float* bl   = (const float*)d_in[7];
  const int* midx = (const int*)d_in[8];
  float* out = (float*)d_out;

  char* ws = (char*)d_ws;
  int* counts  = (int*)ws;                    // 8 ints
  int* cursors = counts + 8;                  // 8 ints
  int* base    = counts + 16;                 // 8 ints
  int* table   = counts + 24;                 // MAXTB*2 ints
  int* bucket  = table + 2 * MAXTB;           // NPTS ints
  size_t off = (((size_t)(24 + 2 * MAXTB + NPTS)) * 4 + 15) & ~(size_t)15;
  unsigned short* Wt0 = (unsigned short*)(ws + off);          // 8*256*32 bf16
  unsigned short* Wth = Wt0 + NCH * 8192;                     // 8*6*256*256 bf16

  hipMemsetAsync(counts, 0, 16 * sizeof(int), stream);        // counts + cursors
  hipLaunchKernelGGL(prep1_k, dim3(840),   dim3(256), 0, stream,
                     Wh, W0, midx, Wth, Wt0, counts);
  hipLaunchKernelGGL(prep2_k, dim3(65),    dim3(256), 0, stream,
                     midx, counts, cursors, base, table, bucket);
  hipLaunchKernelGGL(mlp_k,   dim3(MAXTB), dim3(256), 0, stream,
                     x, proc, b0, bh, Wl, bl, Wt0, Wth, counts, base, table, bucket, out);
}

// Round 7
// 144.173 us; speedup vs baseline: 1.9143x; 1.7680x over previous
//
#include <hip/hip_runtime.h>
#include <hip/hip_bf16.h>
#include <math.h>

#define NPTS   16384
#define NCH    8
#define MT     64    // rows per block
#define LSTR   272   // LDS activation row stride (ushorts), 16B-aligned rows
#define SEG    16384 // fixed bucket segment per chart (worst case all points)

typedef short bf16x8 __attribute__((ext_vector_type(8)));
typedef float f32x4  __attribute__((ext_vector_type(4)));

__device__ __forceinline__ float bf2f(unsigned short u){
  union { unsigned int i; float f; } v; v.i = ((unsigned int)u) << 16; return v.f;
}
__device__ __forceinline__ unsigned short f2bf(float f){
  union { float f; unsigned int i; } v; v.f = f;
  unsigned int x = v.i;
  return (unsigned short)((x + 0x7fffu + ((x >> 16) & 1u)) >> 16); // RNE
}

// ---- single prep kernel ----------------------------------------------------
// blocks 0..767:   Wth[c][l][n][k] = bf16(Wh[c][l][k][n])  (48 mats x 16 tiles)
// blocks 768..775: Wt0[c][n][k]    = bf16(W0[c][k][n]), k padded 29->32
// blocks 776..839: scatter points into fixed per-chart segments (8 atomics/blk)

__global__ __launch_bounds__(256) void prep_k(
    const float* __restrict__ Wh, const float* __restrict__ W0,
    const int* __restrict__ midx,
    unsigned short* __restrict__ Wth, unsigned short* __restrict__ Wt0,
    int* __restrict__ cursors, int* __restrict__ bucket){
  int bid = blockIdx.x, tid = threadIdx.x;
  if (bid < 768){
    __shared__ __align__(16) float tile[64][68];
    int mat = bid >> 4;
    int t4  = bid & 15;
    int kr  = (t4 >> 2) << 6;
    int nc  = (t4 & 3) << 6;
    const float* src = Wh + (size_t)mat * 65536;
    unsigned short* dst = Wth + (size_t)mat * 65536;
    int r  = tid >> 2;
    int cs = (tid & 3) << 4;
    const float* sp = &src[(kr + r) * 256 + nc + cs];
    *(float4*)&tile[r][cs]      = *(const float4*)&sp[0];
    *(float4*)&tile[r][cs + 4]  = *(const float4*)&sp[4];
    *(float4*)&tile[r][cs + 8]  = *(const float4*)&sp[8];
    *(float4*)&tile[r][cs + 12] = *(const float4*)&sp[12];
    __syncthreads();
    int n  = tid >> 2;
    int ks = (tid & 3) << 4;
    __align__(16) unsigned short tmp[16];
    #pragma unroll
    for (int j = 0; j < 16; j++) tmp[j] = f2bf(tile[ks + j][n]);
    *(uint4*)&dst[(nc + n) * 256 + kr + ks]     = *(const uint4*)&tmp[0];
    *(uint4*)&dst[(nc + n) * 256 + kr + ks + 8] = *(const uint4*)&tmp[8];
  } else if (bid < 776){
    int c = bid - 768;
    for (int j = 0; j < 32; j++){
      int i = j * 256 + tid;
      int k = i & 31, n = i >> 5;
      unsigned short v = 0;
      if (k < 29) v = f2bf(W0[(c * 29 + k) * 256 + n]);
      Wt0[c * 8192 + i] = v;
    }
  } else {
    __shared__ int wcnt[4][NCH];
    __shared__ int woff[4][NCH];
    int i = (bid - 776) * 256 + tid;
    int c = midx[i];
    int lane = tid & 63, wv4 = tid >> 6;
    int rk = 0;
    #pragma unroll
    for (int cc = 0; cc < NCH; cc++){
      unsigned long long m = __ballot(c == cc);
      if (lane == cc) wcnt[wv4][cc] = __popcll(m);
      if (c == cc) rk = __popcll(m & ((1ull << lane) - 1));
    }
    __syncthreads();
    if (tid < NCH){
      int c8 = tid;
      int t0 = wcnt[0][c8], t1 = wcnt[1][c8], t2 = wcnt[2][c8], t3 = wcnt[3][c8];
      int gb = atomicAdd(&cursors[c8], t0 + t1 + t2 + t3);
      woff[0][c8] = gb; woff[1][c8] = gb + t0;
      woff[2][c8] = gb + t0 + t1; woff[3][c8] = gb + t0 + t1 + t2;
    }
    __syncthreads();
    bucket[c * SEG + woff[wv4][c] + rk] = i;
  }
}

// ---- main fused MLP: full-layer B slab in VGPRs (compiler-scheduled vmcnt) --

__global__ __launch_bounds__(256, 1) void mlp_k(
    const float* __restrict__ x,
    const float* __restrict__ proc,
    const float* __restrict__ b0,
    const float* __restrict__ bh,
    const float* __restrict__ Wl,
    const float* __restrict__ bl,
    const unsigned short* __restrict__ Wt0,
    const unsigned short* __restrict__ Wth,
    const int* __restrict__ counts,
    const int* __restrict__ bucket,
    float* __restrict__ out)
{
  __shared__ __align__(16) unsigned short act0[MT * LSTR];
  __shared__ __align__(16) unsigned short act1[MT * LSTR];
  __shared__ float biasb[7 * 256];
  __shared__ float wlb[512];
  __shared__ int ridx[MT];

  int chart = blockIdx.x & 7;     // XCD swizzle: consecutive blocks -> different XCDs
  int tile  = blockIdx.x >> 3;
  int cnt   = counts[chart] - tile * MT;
  if (cnt <= 0) return;
  if (cnt > MT) cnt = MT;

  int tid  = threadIdx.x;
  int lane = tid & 63;
  int wv   = tid >> 6;
  int l15  = lane & 15;
  int quad = lane >> 4;
  int nb   = wv * 64;             // this wave's output-column base

  // stage biases + Wl into LDS
  biasb[tid] = b0[chart * 256 + tid];
  #pragma unroll
  for (int j = 0; j < 6; j++)
    biasb[(j + 1) * 256 + tid] = bh[(chart * 6 + j) * 256 + tid];
  wlb[tid]       = Wl[chart * 512 + tid];
  wlb[256 + tid] = Wl[chart * 512 + 256 + tid];

  // positional encoding -> act0 rows
  if (tid < MT){
    int row = tid;
    int g = (row < cnt) ? bucket[chart * SEG + tile * MT + row] : -1;
    ridx[row] = g;
    unsigned short* rowp = &act0[row * LSTR];
    if (g >= 0){
      float xv0 = x[g*3+0], xv1 = x[g*3+1], xv2 = x[g*3+2];
      rowp[0] = f2bf(xv0); rowp[1] = f2bf(xv1); rowp[2] = f2bf(xv2);
      #pragma unroll
      for (int d = 1; d <= 4; d++){
        float s = (float)(1 << d) * 3.14159265358979323846f;
        int o = 3 + (d - 1) * 6;
        rowp[o+0] = f2bf(sinf(s*xv0)); rowp[o+1] = f2bf(sinf(s*xv1)); rowp[o+2] = f2bf(sinf(s*xv2));
        rowp[o+3] = f2bf(cosf(s*xv0)); rowp[o+4] = f2bf(cosf(s*xv1)); rowp[o+5] = f2bf(cosf(s*xv2));
      }
      rowp[27] = f2bf(proc[0]); rowp[28] = f2bf(proc[1]);
      rowp[29] = 0; rowp[30] = 0; rowp[31] = 0;
    } else {
      #pragma unroll
      for (int k = 0; k < 32; k++) rowp[k] = 0;
    }
  }
  __syncthreads();

  f32x4 acc[4][4];
  const f32x4 zz = {0.f, 0.f, 0.f, 0.f};

  // Layer 0: (64x32)@(32x256), single K-step; B slab from Wt0 (global, cached)
  {
    const unsigned short* W0p = Wt0 + chart * 8192;
    bf16x8 b0r[4];
    #pragma unroll
    for (int nt = 0; nt < 4; nt++)
      b0r[nt] = *(const bf16x8*)&W0p[(nb + nt * 16 + l15) * 32 + quad * 8];
    #pragma unroll
    for (int mt = 0; mt < 4; mt++){
      bf16x8 a0 = *(const bf16x8*)&act0[(mt * 16 + l15) * LSTR + quad * 8];
      #pragma unroll
      for (int nt = 0; nt < 4; nt++)
        acc[mt][nt] = __builtin_amdgcn_mfma_f32_16x16x32_bf16(a0, b0r[nt], zz, 0, 0, 0);
    }
    #pragma unroll
    for (int nt = 0; nt < 4; nt++){
      int col = nb + nt * 16 + l15;
      float bias = biasb[col];
      #pragma unroll
      for (int mt = 0; mt < 4; mt++)
        #pragma unroll
        for (int r = 0; r < 4; r++){
          float v = acc[mt][nt][r] + bias;
          v = v > 0.f ? v : 0.f;
          act1[(mt * 16 + quad * 4 + r) * LSTR + col] = f2bf(v);
        }
    }
  }
  __syncthreads();

  // 6 hidden layers: full 64x256 B slab (32 x 16B loads) in flight per wave
  for (int l = 1; l <= 6; l++){
    const unsigned short* wp = Wth + ((size_t)(chart * 6 + l - 1) << 16)
                             + (size_t)(nb + l15) * 256 + quad * 8;
    const unsigned short* ain = (l & 1) ? act1 : act0;
    unsigned short* aout      = (l & 1) ? act0 : act1;

    bf16x8 breg[8][4];
    #pragma unroll
    for (int kk = 0; kk < 8; kk++)
      #pragma unroll
      for (int nt = 0; nt < 4; nt++)
        breg[kk][nt] = *(const bf16x8*)&wp[nt * 4096 + kk * 32];

    #pragma unroll
    for (int mt = 0; mt < 4; mt++){
      bf16x8 a[8];
      #pragma unroll
      for (int kk = 0; kk < 8; kk++)
        a[kk] = *(const bf16x8*)&ain[(mt * 16 + l15) * LSTR + kk * 32 + quad * 8];
      #pragma unroll
      for (int kk = 0; kk < 8; kk++)
        #pragma unroll
        for (int nt = 0; nt < 4; nt++)
          acc[mt][nt] = __builtin_amdgcn_mfma_f32_16x16x32_bf16(
              a[kk], breg[kk][nt], (kk == 0) ? zz : acc[mt][nt], 0, 0, 0);
    }

    #pragma unroll
    for (int nt = 0; nt < 4; nt++){
      int col = nb + nt * 16 + l15;
      float bias = biasb[l * 256 + col];
      #pragma unroll
      for (int mt = 0; mt < 4; mt++)
        #pragma unroll
        for (int r = 0; r < 4; r++){
          float v = acc[mt][nt][r] + bias;
          v = v > 0.f ? v : 0.f;
          aout[(mt * 16 + quad * 4 + r) * LSTR + col] = f2bf(v);
        }
    }
    __syncthreads();
  }

  // Final layer: (64x256)@(256x2) + sigmoid; layer-6 output is in act1
  {
    int m = tid >> 2;
    int p = tid & 3;
    const unsigned short* hrow = act1 + m * LSTR + p * 64;
    const float* wlp = wlb + p * 128;
    float s0 = 0.f, s1 = 0.f;
    #pragma unroll 8
    for (int k = 0; k < 64; k += 2){
      float4 w4 = *(const float4*)&wlp[k * 2];
      unsigned int h2 = *(const unsigned int*)&hrow[k];
      float hv0 = bf2f((unsigned short)(h2 & 0xffff));
      float hv1 = bf2f((unsigned short)(h2 >> 16));
      s0 += hv0 * w4.x + hv1 * w4.z;
      s1 += hv0 * w4.y + hv1 * w4.w;
    }
    s0 += __shfl_xor(s0, 1); s0 += __shfl_xor(s0, 2);
    s1 += __shfl_xor(s1, 1); s1 += __shfl_xor(s1, 2);
    if (p == 0){
      int g = ridx[m];
      if (g >= 0){
        float o0 = 1.f / (1.f + __expf(-(s0 + bl[chart*2+0])));
        float o1 = 1.f / (1.f + __expf(-(s1 + bl[chart*2+1])));
        *(float2*)&out[(size_t)g * 2] = make_float2(o0, o1);
      }
    }
  }
}

// ---- launch ---------------------------------------------------------------

extern "C" void kernel_launch(void* const* d_in, const int* in_sizes, int n_in,
                              void* d_out, int out_size, void* d_ws, size_t ws_size,
                              hipStream_t stream){
  const float* x    = (const float*)d_in[0];
  const float* proc = (const float*)d_in[1];
  const float* W0   = (const float*)d_in[2];
  const float* b0   = (const float*)d_in[3];
  const float* Wh   = (const float*)d_in[4];
  const float* bh   = (const float*)d_in[5];
  const float* Wl   = (const float*)d_in[6];
  const float* bl   = (const float*)d_in[7];
  const int* midx = (const int*)d_in[8];
  float* out = (float*)d_out;

  char* ws = (char*)d_ws;
  int* cursors = (int*)ws;                          // 8 ints (= counts after prep)
  int* bucket  = cursors + 8;                       // NCH * SEG ints
  size_t off = (((size_t)(8 + NCH * SEG)) * 4 + 15) & ~(size_t)15;
  unsigned short* Wt0 = (unsigned short*)(ws + off);  // 8*256*32 bf16
  unsigned short* Wth = Wt0 + NCH * 8192;             // 8*6*256*256 bf16

  hipMemsetAsync(cursors, 0, 8 * sizeof(int), stream);
  hipLaunchKernelGGL(prep_k, dim3(840),  dim3(256), 0, stream,
                     Wh, W0, midx, Wth, Wt0, cursors, bucket);
  hipLaunchKernelGGL(mlp_k,  dim3(2048), dim3(256), 0, stream,
                     x, proc, b0, bh, Wl, bl, Wt0, Wth, cursors, bucket, out);
}